// Round 7
// baseline (489.784 us; speedup 1.0000x reference)
//
#include <hip/hip_runtime.h>
#include <hip/hip_fp16.h>

// ---------------------------------------------------------------------------
// HeteroIncidentGATv2: 3 bipartite GATv2 relations (H=4, C=32, HC=128)
//   hs: host->switch (200K), vh: vm->host (400K), jv: job->vm (800K)
//
// R19 changes vs R18 (406.6us, REGRESSION - alpha fold reverted; rewalk
// re-fetched nxt + ex lines, +190MB. Accounting: e2e = agg3 + mega +
// alpha(18) + init(8) + ~145us harness-fixed):
//   - agg3: R15 structure restored (8 lanes/dst, ex unnormalized + dn,
//     separate alpha kernel) but 128-thread blocks (16 dst) - R18's one
//     clean win was finer-tail occupancy 59->63%.
//   - mega: per-WAVE work-stealing over 16-row strips via atomic ticket
//     (chunks of 8 strips; W-frags reload only on job change). Link waves
//     join GEMM after linking (+23% workers); rounding imbalance gone.
//     Ticket zeroed by init each launch (re-poison safe). No barriers.
//   - init: + job scores (sigmoid(b_job)) + ticket zero.
// ---------------------------------------------------------------------------

#define SLOPE_ATT 0.2f
#define SLOPE_OUT 0.01f
#define CHUNK 8

typedef _Float16 half8_t __attribute__((ext_vector_type(8)));
typedef _Float16 v2h_t __attribute__((ext_vector_type(2)));
typedef float float4_t __attribute__((ext_vector_type(4)));

__device__ __forceinline__ float dot8(half8_t a, half8_t b, float acc) {
    v2h_t a0 = __builtin_shufflevector(a, a, 0, 1);
    v2h_t a1 = __builtin_shufflevector(a, a, 2, 3);
    v2h_t a2 = __builtin_shufflevector(a, a, 4, 5);
    v2h_t a3 = __builtin_shufflevector(a, a, 6, 7);
    v2h_t b0 = __builtin_shufflevector(b, b, 0, 1);
    v2h_t b1 = __builtin_shufflevector(b, b, 2, 3);
    v2h_t b2 = __builtin_shufflevector(b, b, 4, 5);
    v2h_t b3 = __builtin_shufflevector(b, b, 6, 7);
    acc = __builtin_amdgcn_fdot2(a0, b0, acc, false);
    acc = __builtin_amdgcn_fdot2(a1, b1, acc, false);
    acc = __builtin_amdgcn_fdot2(a2, b2, acc, false);
    acc = __builtin_amdgcn_fdot2(a3, b3, acc, false);
    return acc;
}

// ---------------------------------------------------------------------------
// L0: head=-1 + Wt fp16 transpose + job scores (const) + ticket zero.
// ---------------------------------------------------------------------------
struct WSrc { const float* W[6]; };

__global__ __launch_bounds__(256) void init_wt_kernel(
    int* __restrict__ head, int ptot, WSrc wsrc, __half* __restrict__ Wt,
    const float* __restrict__ bjob, float* __restrict__ sjob, int NJ,
    int* __restrict__ ticket) {
    int i = blockIdx.x * 256 + threadIdx.x;
    if (i < ptot) {
        head[i] = -1;
    } else {
        int r = i - ptot;
        if (r < 6 * 8192) {
            int j = r >> 13;           // which W
            int rr = r & 8191;         // n*64 + k
            int n = rr >> 6, k = rr & 63;
            Wt[r] = (__half)wsrc.W[j][k * 128 + n];
        } else {
            int q = r - 6 * 8192;
            if (q < NJ) sjob[q] = 1.f / (1.f + __expf(-bjob[0]));
            else if (q - NJ < 8) ticket[q - NJ] = 0;
        }
    }
}

// ---------------------------------------------------------------------------
// Linked-list build: old = atomicExch(&head[slot], le); nxt[ge] = {old, src}
// ---------------------------------------------------------------------------
__device__ __forceinline__ void link_work(
    int linkId, int linkBlocks,
    const int* __restrict__ d0, const int* __restrict__ s0,
    const int* __restrict__ d1, const int* __restrict__ s1,
    const int* __restrict__ d2, const int* __restrict__ s2,
    int* __restrict__ head, int2* __restrict__ nxt,
    int E0, int E1, int E2, int pb1, int pb2) {
    int i = linkId * 256 + threadIdx.x;
    int Etot = E0 + E1 + E2;
    int stride = linkBlocks * 256;
    for (; i < Etot; i += stride) {
        int le, slot; const int* sp;
        if (i < E0)           { le = i;           slot = d0[le];       sp = s0; }
        else if (i < E0 + E1) { le = i - E0;      slot = pb1 + d1[le]; sp = s1; }
        else                  { le = i - E0 - E1; slot = pb2 + d2[le]; sp = s2; }
        int old = atomicExch(&head[slot], le);
        nxt[i] = make_int2(old, sp[le]);
    }
}

// ---------------------------------------------------------------------------
// Mega: link3 (first LB blocks, then they join GEMM) + ticket-stolen GEMM.
// Work unit = 16-row strip per WAVE; chunks of CHUNK strips per ticket.
// Frag layouts (gfx950 16x16x32): A[m=lane&15][k=quad*8+j],
// B[n=lane&15][k=quad*8+j], C/D col=lane&15, row=quad*4+reg.
// W frags reloaded only on job change (<= once per chunk typically).
// X prefetched 1 strip ahead within a chunk. No barriers (wave-private sY).
// ---------------------------------------------------------------------------
struct GemmJobs {
    const float* X[6]; const float* b[6]; __half* Y[6];
    int M[6]; int sbase[7];     // strip (16-row) bases, cumulative
};

__global__ __launch_bounds__(256) void mega_gemm_link_kernel(
    GemmJobs j, const __half* __restrict__ Wt, int* __restrict__ ticket,
    int LB,
    const int* __restrict__ d0, const int* __restrict__ s0,
    const int* __restrict__ d1, const int* __restrict__ s1,
    const int* __restrict__ d2, const int* __restrict__ s2,
    int* __restrict__ head, int2* __restrict__ nxt,
    int E0, int E1, int E2, int pb1, int pb2) {
    __shared__ __half sY[4][16][136];
    int b = blockIdx.x;
    if (b < LB)
        link_work(b, LB, d0, s0, d1, s1, d2, s2, head, nxt, E0, E1, E2, pb1, pb2);

    const int lane = threadIdx.x & 63;
    const int wv = threadIdx.x >> 6;
    const int mr = lane & 15;
    const int quad = lane >> 4;
    const int nbtot = j.sbase[6];

    int kc = -1;                      // job whose W is currently in regs
    half8_t wb0[8], wb1[8];
    float bv[8];

    for (;;) {
        int c = 0;
        if (lane == 0) c = atomicAdd(ticket, 1);
        c = __shfl(c, 0);
        int g0 = c * CHUNK;
        if (g0 >= nbtot) break;
        int g1 = g0 + CHUNK; if (g1 > nbtot) g1 = nbtot;

        // locate job of first strip; load its X
        int k = 0;
        while (g0 >= j.sbase[k + 1]) k++;
        float4 xc0 = {}, xc1 = {}, xc2 = {}, xc3 = {};
        {
            int gr = (g0 - j.sbase[k]) * 16 + mr;
            if (gr < j.M[k]) {
                const float* X = j.X[k];
                const float4* xp = (const float4*)(X + (size_t)gr * 64 + quad * 8);
                xc0 = xp[0]; xc1 = xp[1];
                const float4* xq = (const float4*)(X + (size_t)gr * 64 + 32 + quad * 8);
                xc2 = xq[0]; xc3 = xq[1];
            }
        }

        for (int g = g0; g < g1; ++g) {
            // prefetch next strip's X (in flight across this strip's compute)
            float4 xn0 = {}, xn1 = {}, xn2 = {}, xn3 = {};
            int kn = k;
            if (g + 1 < g1) {
                while (g + 1 >= j.sbase[kn + 1]) kn++;
                int gr = (g + 1 - j.sbase[kn]) * 16 + mr;
                if (gr < j.M[kn]) {
                    const float* X = j.X[kn];
                    const float4* xp = (const float4*)(X + (size_t)gr * 64 + quad * 8);
                    xn0 = xp[0]; xn1 = xp[1];
                    const float4* xq = (const float4*)(X + (size_t)gr * 64 + 32 + quad * 8);
                    xn2 = xq[0]; xn3 = xq[1];
                }
            }

            // W fragments for this job (reload only on job change)
            if (k != kc) {
                kc = k;
                const __half* W = Wt + (size_t)k * 8192;
                const float* bb_ = j.b[k];
#pragma unroll
                for (int t = 0; t < 8; t++) {
                    const __half* wp = W + ((size_t)(t * 16 + mr)) * 64 + quad * 8;
                    wb0[t] = *(const half8_t*)wp;
                    wb1[t] = *(const half8_t*)(wp + 32);
                    bv[t] = bb_[t * 16 + mr];
                }
            }

            half8_t a0, a1;
            a0[0] = (_Float16)xc0.x; a0[1] = (_Float16)xc0.y;
            a0[2] = (_Float16)xc0.z; a0[3] = (_Float16)xc0.w;
            a0[4] = (_Float16)xc1.x; a0[5] = (_Float16)xc1.y;
            a0[6] = (_Float16)xc1.z; a0[7] = (_Float16)xc1.w;
            a1[0] = (_Float16)xc2.x; a1[1] = (_Float16)xc2.y;
            a1[2] = (_Float16)xc2.z; a1[3] = (_Float16)xc2.w;
            a1[4] = (_Float16)xc3.x; a1[5] = (_Float16)xc3.y;
            a1[6] = (_Float16)xc3.z; a1[7] = (_Float16)xc3.w;

            const int M = j.M[k];
            __half* __restrict__ Y = j.Y[k];
            const int m0 = (g - j.sbase[k]) * 16;
#pragma unroll
            for (int tt = 0; tt < 8; tt++) {
                float4_t creg = {0.f, 0.f, 0.f, 0.f};
                creg = __builtin_amdgcn_mfma_f32_16x16x32_f16(a0, wb0[tt], creg, 0, 0, 0);
                creg = __builtin_amdgcn_mfma_f32_16x16x32_f16(a1, wb1[tt], creg, 0, 0, 0);
                int ocol = tt * 16 + mr;
                int lrow = quad * 4;
#pragma unroll
                for (int r = 0; r < 4; r++)
                    sY[wv][lrow + r][ocol] = (__half)(creg[r] + bv[tt]);
            }

            // wave-private LDS transpose -> coalesced 16B stores (no barrier)
            const int c8 = mr * 8;
#pragma unroll
            for (int i = 0; i < 4; i++) {
                int row = i * 4 + quad;
                int gr2 = m0 + row;
                if (gr2 < M) {
                    half8_t v = *(const half8_t*)&sY[wv][row][c8];
                    *(half8_t*)&Y[(size_t)gr2 * 128 + c8] = v;
                }
            }

            xc0 = xn0; xc1 = xn1; xc2 = xn2; xc3 = xn3;
            k = kn;
        }
    }
}

// ---------------------------------------------------------------------------
// Fused GATv2 aggregate: 16 dst per 128-thread block (8 lanes/dst, 16 ch/ln).
// Per edge: in-lane fdot2 + one shfl -> head logit; w = exp(p); acc += w*x;
// ex[e] = w (unnormalized), dn[d] = ssum. Fused readout epilogue.
// ---------------------------------------------------------------------------
struct AggJob {
    const __half* xl; const __half* xr; const float* att;
    const int* head; const int2* nxt;
    float* ex; float* dn;
    const float* bias; const float* Wn; const float* bn; float* scores;
    int Nd;
};
struct AggJobs { AggJob r[3]; int base[4]; };   // base in BLOCKS (16 dst/block)

__global__ __launch_bounds__(128) void agg3_kernel(AggJobs aj) {
    int b = blockIdx.x;
    int k = 0;
    while (b >= aj.base[k + 1]) k++;
    AggJob J = aj.r[k];

    const int l = threadIdx.x & 63;
    const int wv = threadIdx.x >> 6;      // 0..1
    const int li = l & 7;                 // lane in group
    const int g = l >> 3;                 // group 0..7
    const int dbase = ((b - aj.base[k]) * 2 + wv) * 8;
    const int d = dbase + g;
    if (dbase >= J.Nd) return;
    const bool dok = d < J.Nd;
    const int h = li >> 1;                // my head (pair of lanes per head)

    // my 16 channels: 2 x half8
    half8_t xr0 = {}, xr1 = {};
    if (dok) {
        const half8_t* xrp = (const half8_t*)(J.xr + (size_t)d * 128) + li * 2;
        xr0 = xrp[0]; xr1 = xrp[1];
    }
    half8_t at0, at1;
    {
        const float* ap = J.att + li * 16;
#pragma unroll
        for (int i = 0; i < 8; i++) {
            at0[i] = (_Float16)ap[i];
            at1[i] = (_Float16)ap[8 + i];
        }
    }
    const half8_t sl8 = {(_Float16)SLOPE_ATT, (_Float16)SLOPE_ATT,
                         (_Float16)SLOPE_ATT, (_Float16)SLOPE_ATT,
                         (_Float16)SLOPE_ATT, (_Float16)SLOPE_ATT,
                         (_Float16)SLOPE_ATT, (_Float16)SLOPE_ATT};

    float acc[16] = {};
    float ssum = 0.f;

    int e = dok ? J.head[d] : -1;
    const bool any = (e >= 0);

    while (__any(e >= 0)) {
        bool act = (e >= 0);
        int2 ns = act ? J.nxt[e] : make_int2(-1, 0);
        half8_t x0 = {}, x1 = {};
        if (act) {
            const half8_t* xp = (const half8_t*)(J.xl + (size_t)ns.y * 128) + li * 2;
            x0 = xp[0]; x1 = xp[1];
        }
        if (act) {
            half8_t v0 = x0 + xr0;
            half8_t v1 = x1 + xr1;
            half8_t lk0 = __builtin_elementwise_max(v0, v0 * sl8);
            half8_t lk1 = __builtin_elementwise_max(v1, v1 * sl8);
            float p = dot8(lk1, at1, dot8(lk0, at0, 0.f));
            p += __shfl_xor(p, 1);            // pair shares one head
            float w = __expf(p);
            if ((li & 1) == 0) J.ex[(size_t)e * 4 + h] = w;
            ssum += w;
#pragma unroll
            for (int i = 0; i < 8; i++) {
                acc[i]     += w * (float)x0[i];
                acc[8 + i] += w * (float)x1[i];
            }
        }
        e = act ? ns.x : -1;
    }

    if (dok && (li & 1) == 0) J.dn[(size_t)d * 4 + h] = ssum;

    // readout: sigmoid(lrelu(acc/ssum + bias, .01) . Wn + bn)
    float rr = any ? 1.f / ssum : 0.f;
    float pr = 0.f;
    if (dok) {
        const float* bp = J.bias + li * 16;
        const float* wp = J.Wn + li * 16;
#pragma unroll
        for (int i = 0; i < 16; i++) {
            float o = acc[i] * rr + bp[i];
            o = o > 0.f ? o : SLOPE_OUT * o;
            pr += o * wp[i];
        }
    }
    pr += __shfl_xor(pr, 1);
    pr += __shfl_xor(pr, 2);
    pr += __shfl_xor(pr, 4);
    if (dok && li == 0)
        J.scores[d] = 1.f / (1.f + __expf(-(pr + J.bn[0])));
}

// ---------------------------------------------------------------------------
// alpha = ex/dn for all relations (job scores handled in init).
// ---------------------------------------------------------------------------
__global__ __launch_bounds__(256) void alpha_kernel(
    float* __restrict__ ex,
    const int* __restrict__ d0, const int* __restrict__ d1,
    const int* __restrict__ d2,
    const float* __restrict__ dn,
    int E0, int E1, int E2, int pb1, int pb2) {
    int i = blockIdx.x * 256 + threadIdx.x;
    int tot = (E0 + E1 + E2) * 4;
    if (i >= tot) return;
    int e = i >> 2, h = i & 3;
    int d;
    if (e < E0)           d = d0[e];
    else if (e < E0 + E1) d = pb1 + d1[e - E0];
    else                  d = pb2 + d2[e - E0 - E1];
    ex[i] = ex[i] / dn[(size_t)d * 4 + h];
}

// ---------------------------------------------------------------------------

extern "C" void kernel_launch(void* const* d_in, const int* in_sizes, int n_in,
                              void* d_out, int out_size, void* d_ws, size_t ws_size,
                              hipStream_t stream) {
    const float* x_host   = (const float*)d_in[0];
    const float* x_vm     = (const float*)d_in[1];
    const float* x_job    = (const float*)d_in[2];
    const float* x_switch = (const float*)d_in[3];
    const int* e_hs_src = (const int*)d_in[4];
    const int* e_hs_dst = (const int*)d_in[5];
    const int* e_vh_src = (const int*)d_in[6];
    const int* e_vh_dst = (const int*)d_in[7];
    const int* e_jv_src = (const int*)d_in[8];
    const int* e_jv_dst = (const int*)d_in[9];
    const float* Wl_hs = (const float*)d_in[10];
    const float* bl_hs = (const float*)d_in[11];
    const float* Wr_hs = (const float*)d_in[12];
    const float* br_hs = (const float*)d_in[13];
    const float* att_hs = (const float*)d_in[14];
    const float* bias_hs = (const float*)d_in[15];
    const float* Wl_vh = (const float*)d_in[16];
    const float* bl_vh = (const float*)d_in[17];
    const float* Wr_vh = (const float*)d_in[18];
    const float* br_vh = (const float*)d_in[19];
    const float* att_vh = (const float*)d_in[20];
    const float* bias_vh = (const float*)d_in[21];
    const float* Wl_jv = (const float*)d_in[22];
    const float* bl_jv = (const float*)d_in[23];
    const float* Wr_jv = (const float*)d_in[24];
    const float* br_jv = (const float*)d_in[25];
    const float* att_jv = (const float*)d_in[26];
    const float* bias_jv = (const float*)d_in[27];
    const float* W_host   = (const float*)d_in[28];
    const float* b_host   = (const float*)d_in[29];
    const float* W_vm     = (const float*)d_in[30];
    const float* b_vm     = (const float*)d_in[31];
    const float* W_job    = (const float*)d_in[32];
    const float* b_job    = (const float*)d_in[33];
    const float* W_switch = (const float*)d_in[34];
    const float* b_switch = (const float*)d_in[35];

    const int NH  = in_sizes[0] / 64;
    const int NV  = in_sizes[1] / 64;
    const int NJ  = in_sizes[2] / 64;
    const int NSW = in_sizes[3] / 64;
    const int EHS = in_sizes[4];
    const int EVH = in_sizes[6];
    const int EJV = in_sizes[8];
    const int Etot = EHS + EVH + EJV;

    float* out = (float*)d_out;
    float* s_host = out;
    float* s_vm = out + NH;
    float* s_job = out + NH + NV;
    float* s_sw = out + NH + NV + NJ;
    float* a_hs = out + NH + NV + NJ + NSW;
    float* a_vh = a_hs + (size_t)EHS * 4;
    float* a_jv = a_vh + (size_t)EVH * 4;

    const int pb1 = ((NSW + 255) / 256) * 256;
    const int pb2 = pb1 + ((NH + 255) / 256) * 256;
    const int ptot = pb2 + ((NV + 255) / 256) * 256;

    // -------- ws layout (~137 MB total) --------
    float* ws = (float*)d_ws;
    int2* nxt_all = (int2*)ws;                              // Etot int2
    int* head_all = (int*)(nxt_all + Etot);                 // ptot
    float* dn_all = (float*)(head_all + ptot);              // ptot*4
    int* ticket   = (int*)(dn_all + (size_t)ptot * 4);      // 8 ints (32B)
    __half* Wt    = (__half*)(ticket + 8);                  // 6*8192 fp16
    __half* mats  = Wt + 6 * 8192;
    __half* xl_hs = mats;                                   // NH*128
    __half* xr_hs = xl_hs + (size_t)NH * 128;               // NSW*128
    __half* xl_vh = xr_hs + (size_t)NSW * 128;              // NV*128
    __half* xr_vh = xl_vh + (size_t)NV * 128;               // NH*128
    __half* xl_jv = xr_vh + (size_t)NH * 128;               // NJ*128
    __half* xr_jv = xl_jv + (size_t)NJ * 128;               // NV*128

    // L0: head = -1 + Wt conversion + job scores + ticket zero
    {
        WSrc w;
        w.W[0] = Wl_hs; w.W[1] = Wr_hs; w.W[2] = Wl_vh;
        w.W[3] = Wr_vh; w.W[4] = Wl_jv; w.W[5] = Wr_jv;
        int tot = ptot + 6 * 8192 + NJ + 8;
        init_wt_kernel<<<(tot + 255) / 256, 256, 0, stream>>>(
            head_all, ptot, w, Wt, b_job, s_job, NJ, ticket);
    }

    // L1: mega = link3 + ticket-stolen persistent GEMM (16-row strips)
    {
        GemmJobs j;
        const float* Xs[6] = {x_host, x_switch, x_vm, x_host, x_job, x_vm};
        const float* bs[6] = {bl_hs, br_hs, bl_vh, br_vh, bl_jv, br_jv};
        __half* Ys[6] = {xl_hs, xr_hs, xl_vh, xr_vh, xl_jv, xr_jv};
        int Ms[6] = {NH, NSW, NV, NH, NJ, NV};
        int sb = 0;
        for (int k = 0; k < 6; k++) {
            j.X[k] = Xs[k]; j.b[k] = bs[k]; j.Y[k] = Ys[k]; j.M[k] = Ms[k];
            j.sbase[k] = sb;
            sb += (Ms[k] + 15) / 16;
        }
        j.sbase[6] = sb;
        const int LB = 384;
        const int T = 2048;     // same grid shape as R15; stealing balances
        mega_gemm_link_kernel<<<T, 256, 0, stream>>>(
            j, Wt, ticket, LB, e_hs_dst, e_hs_src, e_vh_dst, e_vh_src,
            e_jv_dst, e_jv_src, head_all, nxt_all, EHS, EVH, EJV, pb1, pb2);
    }

    // L2: merged agg (3 relations, 16 dst per 128-thread block)
    {
        AggJobs aj;
        aj.r[0] = {xl_hs, xr_hs, att_hs, head_all + 0, nxt_all + 0,
                   a_hs, dn_all + 0,
                   bias_hs, W_switch, b_switch, s_sw, NSW};
        aj.r[1] = {xl_vh, xr_vh, att_vh, head_all + pb1, nxt_all + EHS,
                   a_vh, dn_all + (size_t)pb1 * 4,
                   bias_vh, W_host, b_host, s_host, NH};
        aj.r[2] = {xl_jv, xr_jv, att_jv, head_all + pb2, nxt_all + (EHS + EVH),
                   a_jv, dn_all + (size_t)pb2 * 4,
                   bias_jv, W_vm, b_vm, s_vm, NV};
        aj.base[0] = 0;
        aj.base[1] = (NSW + 15) / 16;
        aj.base[2] = aj.base[1] + (NH + 15) / 16;
        aj.base[3] = aj.base[2] + (NV + 15) / 16;
        agg3_kernel<<<aj.base[3], 128, 0, stream>>>(aj);
    }

    // L3: alpha (all relations)
    {
        int ab = (Etot * 4 + 255) / 256;
        alpha_kernel<<<ab, 256, 0, stream>>>(
            a_hs, e_hs_dst, e_vh_dst, e_jv_dst, dn_all,
            EHS, EVH, EJV, pb1, pb2);
    }
}

// Round 8
// 406.532 us; speedup vs baseline: 1.2048x; 1.2048x over previous
//
#include <hip/hip_runtime.h>
#include <hip/hip_fp16.h>

// ---------------------------------------------------------------------------
// HeteroIncidentGATv2: 3 bipartite GATv2 relations (H=4, C=32, HC=128)
//   hs: host->switch (200K), vh: vm->host (400K), jv: job->vm (800K)
//
// R20 changes vs R19 (489.8us, REGRESSION - stealing reverted: 3946 chunks
// < 8192 waves halved working parallelism):
//   - full revert to R15 (best measured, 367.5us): static per-job persistent
//     GEMM partition, agg3 256-thread/32-dst blocks, separate alpha.
//   - mega SPLIT into two kernels to isolate the unexplained 90us:
//     gemm_kernel (2048 blocks, pure persistent GEMM, no link interleave)
//     + link_kernel (768 blocks, grid-stride atomicExch chain build).
//     GEMM stream (220MB seq) should run ~40-60us alone if the merged
//     kernel's cost was atomic/fabric interference from link.
//   - init: + job scores (sigmoid(b_job), input-independent).
// ---------------------------------------------------------------------------

#define SLOPE_ATT 0.2f
#define SLOPE_OUT 0.01f

typedef _Float16 half8_t __attribute__((ext_vector_type(8)));
typedef _Float16 v2h_t __attribute__((ext_vector_type(2)));
typedef float float4_t __attribute__((ext_vector_type(4)));

__device__ __forceinline__ float dot8(half8_t a, half8_t b, float acc) {
    v2h_t a0 = __builtin_shufflevector(a, a, 0, 1);
    v2h_t a1 = __builtin_shufflevector(a, a, 2, 3);
    v2h_t a2 = __builtin_shufflevector(a, a, 4, 5);
    v2h_t a3 = __builtin_shufflevector(a, a, 6, 7);
    v2h_t b0 = __builtin_shufflevector(b, b, 0, 1);
    v2h_t b1 = __builtin_shufflevector(b, b, 2, 3);
    v2h_t b2 = __builtin_shufflevector(b, b, 4, 5);
    v2h_t b3 = __builtin_shufflevector(b, b, 6, 7);
    acc = __builtin_amdgcn_fdot2(a0, b0, acc, false);
    acc = __builtin_amdgcn_fdot2(a1, b1, acc, false);
    acc = __builtin_amdgcn_fdot2(a2, b2, acc, false);
    acc = __builtin_amdgcn_fdot2(a3, b3, acc, false);
    return acc;
}

// ---------------------------------------------------------------------------
// L0: head = -1 + Wt fp16 transpose + job scores (= sigmoid(b_job), const).
// ---------------------------------------------------------------------------
struct WSrc { const float* W[6]; };

__global__ __launch_bounds__(256) void init_wt_kernel(
    int* __restrict__ head, int ptot, WSrc wsrc, __half* __restrict__ Wt,
    const float* __restrict__ bjob, float* __restrict__ sjob, int NJ) {
    int i = blockIdx.x * 256 + threadIdx.x;
    if (i < ptot) {
        head[i] = -1;
    } else {
        int r = i - ptot;
        if (r < 6 * 8192) {
            int j = r >> 13;           // which W
            int rr = r & 8191;         // n*64 + k
            int n = rr >> 6, k = rr & 63;
            Wt[r] = (__half)wsrc.W[j][k * 128 + n];
        } else {
            int q = r - 6 * 8192;
            if (q < NJ) sjob[q] = 1.f / (1.f + __expf(-bjob[0]));
        }
    }
}

// ---------------------------------------------------------------------------
// Linked-list build (standalone): old = atomicExch(&head[slot], le);
// nxt[ge] = {old, src}. Grid-stride over all three relations.
// ---------------------------------------------------------------------------
__global__ __launch_bounds__(256) void link_kernel(
    const int* __restrict__ d0, const int* __restrict__ s0,
    const int* __restrict__ d1, const int* __restrict__ s1,
    const int* __restrict__ d2, const int* __restrict__ s2,
    int* __restrict__ head, int2* __restrict__ nxt,
    int E0, int E1, int E2, int pb1, int pb2) {
    int i = blockIdx.x * 256 + threadIdx.x;
    int Etot = E0 + E1 + E2;
    int stride = gridDim.x * 256;
    for (; i < Etot; i += stride) {
        int le, slot; const int* sp;
        if (i < E0)           { le = i;           slot = d0[le];       sp = s0; }
        else if (i < E0 + E1) { le = i - E0;      slot = pb1 + d1[le]; sp = s1; }
        else                  { le = i - E0 - E1; slot = pb2 + d2[le]; sp = s2; }
        int old = atomicExch(&head[slot], le);
        nxt[i] = make_int2(old, sp[le]);
    }
}

// ---------------------------------------------------------------------------
// Pure persistent GEMM workers (job-partitioned, tile stride loop).
// Frag layouts (gfx950 16x16x32): A[m=lane&15][k=quad*8+j],
// B[n=lane&15][k=quad*8+j], C/D col=lane&15, row=quad*4+reg.
// W frags + bias are loop-invariant registers; X prefetched 1 tile ahead.
// No barrier: sY[wv] slice is wave-private, DS pipe is in-order per wave.
// ---------------------------------------------------------------------------
struct GemmJobs {
    const float* X[6]; const float* b[6]; __half* Y[6];
    int M[6]; int pbase[7];     // pbase: persistent-block partition
};

__global__ __launch_bounds__(256) void gemm_kernel(
    GemmJobs j, const __half* __restrict__ Wt) {
    __shared__ __half sY[4][16][136];
    int bb = blockIdx.x;
    int k = 0;
    while (bb >= j.pbase[k + 1]) k++;
    const int p = bb - j.pbase[k];
    const int gb = j.pbase[k + 1] - j.pbase[k];
    const int M = j.M[k];
    const int nb = (M + 63) >> 6;
    if (p >= nb) return;
    const float* __restrict__ X = j.X[k];
    __half* __restrict__ Y = j.Y[k];
    const float* __restrict__ bb_ = j.b[k];
    const __half* __restrict__ W = Wt + (size_t)k * 8192;

    const int lane = threadIdx.x & 63;
    const int wv = threadIdx.x >> 6;
    const int mr = lane & 15;
    const int quad = lane >> 4;

    // loop-invariant: all 16 W fragments + 8 bias values live in registers
    half8_t wb0[8], wb1[8];
    float bv[8];
#pragma unroll
    for (int t = 0; t < 8; t++) {
        const __half* wp = W + ((size_t)(t * 16 + mr)) * 64 + quad * 8;
        wb0[t] = *(const half8_t*)wp;
        wb1[t] = *(const half8_t*)(wp + 32);
        bv[t] = bb_[t * 16 + mr];
    }

    // prefetch first X tile
    float4 xc0 = {}, xc1 = {}, xc2 = {}, xc3 = {};
    {
        int gr = p * 64 + wv * 16 + mr;
        if (gr < M) {
            const float4* xp = (const float4*)(X + (size_t)gr * 64 + quad * 8);
            xc0 = xp[0]; xc1 = xp[1];
            const float4* xq = (const float4*)(X + (size_t)gr * 64 + 32 + quad * 8);
            xc2 = xq[0]; xc3 = xq[1];
        }
    }

    for (int t = p; t < nb; t += gb) {
        // issue next tile's X loads first (in flight across this iteration)
        int tn = t + gb;
        float4 xn0 = {}, xn1 = {}, xn2 = {}, xn3 = {};
        if (tn < nb) {
            int gr = tn * 64 + wv * 16 + mr;
            if (gr < M) {
                const float4* xp = (const float4*)(X + (size_t)gr * 64 + quad * 8);
                xn0 = xp[0]; xn1 = xp[1];
                const float4* xq = (const float4*)(X + (size_t)gr * 64 + 32 + quad * 8);
                xn2 = xq[0]; xn3 = xq[1];
            }
        }

        half8_t a0, a1;
        a0[0] = (_Float16)xc0.x; a0[1] = (_Float16)xc0.y;
        a0[2] = (_Float16)xc0.z; a0[3] = (_Float16)xc0.w;
        a0[4] = (_Float16)xc1.x; a0[5] = (_Float16)xc1.y;
        a0[6] = (_Float16)xc1.z; a0[7] = (_Float16)xc1.w;
        a1[0] = (_Float16)xc2.x; a1[1] = (_Float16)xc2.y;
        a1[2] = (_Float16)xc2.z; a1[3] = (_Float16)xc2.w;
        a1[4] = (_Float16)xc3.x; a1[5] = (_Float16)xc3.y;
        a1[6] = (_Float16)xc3.z; a1[7] = (_Float16)xc3.w;

        const int m0 = t * 64 + wv * 16;
#pragma unroll
        for (int tt = 0; tt < 8; tt++) {
            float4_t c = {0.f, 0.f, 0.f, 0.f};
            c = __builtin_amdgcn_mfma_f32_16x16x32_f16(a0, wb0[tt], c, 0, 0, 0);
            c = __builtin_amdgcn_mfma_f32_16x16x32_f16(a1, wb1[tt], c, 0, 0, 0);
            int ocol = tt * 16 + mr;
            int lrow = quad * 4;
#pragma unroll
            for (int r = 0; r < 4; r++)
                sY[wv][lrow + r][ocol] = (__half)(c[r] + bv[tt]);
        }

        // wave-private LDS transpose -> coalesced 16B stores (no barrier)
        const int c8 = mr * 8;
#pragma unroll
        for (int i = 0; i < 4; i++) {
            int row = i * 4 + quad;
            int gr2 = m0 + row;
            if (gr2 < M) {
                half8_t v = *(const half8_t*)&sY[wv][row][c8];
                *(half8_t*)&Y[(size_t)gr2 * 128 + c8] = v;
            }
        }

        xc0 = xn0; xc1 = xn1; xc2 = xn2; xc3 = xn3;
    }
}

// ---------------------------------------------------------------------------
// Fused GATv2 aggregate: 32 dst per 256-thread block (8 lanes/dst, 16 ch/ln).
// Per edge: in-lane fdot2 + one shfl -> head logit; w = exp(p); acc += w*x;
// ex[e] = w (unnormalized), dn[d] = ssum. Fused readout epilogue.
// ---------------------------------------------------------------------------
struct AggJob {
    const __half* xl; const __half* xr; const float* att;
    const int* head; const int2* nxt;
    float* ex; float* dn;
    const float* bias; const float* Wn; const float* bn; float* scores;
    int Nd;
};
struct AggJobs { AggJob r[3]; int base[4]; };   // base in BLOCKS (32 dst/block)

__global__ __launch_bounds__(256) void agg3_kernel(AggJobs aj) {
    int b = blockIdx.x;
    int k = 0;
    while (b >= aj.base[k + 1]) k++;
    AggJob J = aj.r[k];

    const int l = threadIdx.x & 63;
    const int wv = threadIdx.x >> 6;
    const int li = l & 7;                 // lane in group
    const int g = l >> 3;                 // group 0..7
    const int dbase = ((b - aj.base[k]) * 4 + wv) * 8;
    const int d = dbase + g;
    if (dbase >= J.Nd) return;
    const bool dok = d < J.Nd;
    const int h = li >> 1;                // my head (pair of lanes per head)

    // my 16 channels: 2 x half8
    half8_t xr0 = {}, xr1 = {};
    if (dok) {
        const half8_t* xrp = (const half8_t*)(J.xr + (size_t)d * 128) + li * 2;
        xr0 = xrp[0]; xr1 = xrp[1];
    }
    half8_t at0, at1;
    {
        const float* ap = J.att + li * 16;
#pragma unroll
        for (int i = 0; i < 8; i++) {
            at0[i] = (_Float16)ap[i];
            at1[i] = (_Float16)ap[8 + i];
        }
    }
    const half8_t sl8 = {(_Float16)SLOPE_ATT, (_Float16)SLOPE_ATT,
                         (_Float16)SLOPE_ATT, (_Float16)SLOPE_ATT,
                         (_Float16)SLOPE_ATT, (_Float16)SLOPE_ATT,
                         (_Float16)SLOPE_ATT, (_Float16)SLOPE_ATT};

    float acc[16] = {};
    float ssum = 0.f;

    int e = dok ? J.head[d] : -1;
    const bool any = (e >= 0);

    while (__any(e >= 0)) {
        bool act = (e >= 0);
        int2 ns = act ? J.nxt[e] : make_int2(-1, 0);
        half8_t x0 = {}, x1 = {};
        if (act) {
            const half8_t* xp = (const half8_t*)(J.xl + (size_t)ns.y * 128) + li * 2;
            x0 = xp[0]; x1 = xp[1];
        }
        if (act) {
            half8_t v0 = x0 + xr0;
            half8_t v1 = x1 + xr1;
            half8_t lk0 = __builtin_elementwise_max(v0, v0 * sl8);
            half8_t lk1 = __builtin_elementwise_max(v1, v1 * sl8);
            float p = dot8(lk1, at1, dot8(lk0, at0, 0.f));
            p += __shfl_xor(p, 1);            // pair shares one head
            float w = __expf(p);
            if ((li & 1) == 0) J.ex[(size_t)e * 4 + h] = w;
            ssum += w;
#pragma unroll
            for (int i = 0; i < 8; i++) {
                acc[i]     += w * (float)x0[i];
                acc[8 + i] += w * (float)x1[i];
            }
        }
        e = act ? ns.x : -1;
    }

    if (dok && (li & 1) == 0) J.dn[(size_t)d * 4 + h] = ssum;

    // readout: sigmoid(lrelu(acc/ssum + bias, .01) . Wn + bn)
    float rr = any ? 1.f / ssum : 0.f;
    float pr = 0.f;
    if (dok) {
        const float* bp = J.bias + li * 16;
        const float* wp = J.Wn + li * 16;
#pragma unroll
        for (int i = 0; i < 16; i++) {
            float o = acc[i] * rr + bp[i];
            o = o > 0.f ? o : SLOPE_OUT * o;
            pr += o * wp[i];
        }
    }
    pr += __shfl_xor(pr, 1);
    pr += __shfl_xor(pr, 2);
    pr += __shfl_xor(pr, 4);
    if (dok && li == 0)
        J.scores[d] = 1.f / (1.f + __expf(-(pr + J.bn[0])));
}

// ---------------------------------------------------------------------------
// alpha = ex/dn for all relations (job scores handled in init).
// ---------------------------------------------------------------------------
__global__ __launch_bounds__(256) void alpha_kernel(
    float* __restrict__ ex,
    const int* __restrict__ d0, const int* __restrict__ d1,
    const int* __restrict__ d2,
    const float* __restrict__ dn,
    int E0, int E1, int E2, int pb1, int pb2) {
    int i = blockIdx.x * 256 + threadIdx.x;
    int tot = (E0 + E1 + E2) * 4;
    if (i >= tot) return;
    int e = i >> 2, h = i & 3;
    int d;
    if (e < E0)           d = d0[e];
    else if (e < E0 + E1) d = pb1 + d1[e - E0];
    else                  d = pb2 + d2[e - E0 - E1];
    ex[i] = ex[i] / dn[(size_t)d * 4 + h];
}

// ---------------------------------------------------------------------------

extern "C" void kernel_launch(void* const* d_in, const int* in_sizes, int n_in,
                              void* d_out, int out_size, void* d_ws, size_t ws_size,
                              hipStream_t stream) {
    const float* x_host   = (const float*)d_in[0];
    const float* x_vm     = (const float*)d_in[1];
    const float* x_job    = (const float*)d_in[2];
    const float* x_switch = (const float*)d_in[3];
    const int* e_hs_src = (const int*)d_in[4];
    const int* e_hs_dst = (const int*)d_in[5];
    const int* e_vh_src = (const int*)d_in[6];
    const int* e_vh_dst = (const int*)d_in[7];
    const int* e_jv_src = (const int*)d_in[8];
    const int* e_jv_dst = (const int*)d_in[9];
    const float* Wl_hs = (const float*)d_in[10];
    const float* bl_hs = (const float*)d_in[11];
    const float* Wr_hs = (const float*)d_in[12];
    const float* br_hs = (const float*)d_in[13];
    const float* att_hs = (const float*)d_in[14];
    const float* bias_hs = (const float*)d_in[15];
    const float* Wl_vh = (const float*)d_in[16];
    const float* bl_vh = (const float*)d_in[17];
    const float* Wr_vh = (const float*)d_in[18];
    const float* br_vh = (const float*)d_in[19];
    const float* att_vh = (const float*)d_in[20];
    const float* bias_vh = (const float*)d_in[21];
    const float* Wl_jv = (const float*)d_in[22];
    const float* bl_jv = (const float*)d_in[23];
    const float* Wr_jv = (const float*)d_in[24];
    const float* br_jv = (const float*)d_in[25];
    const float* att_jv = (const float*)d_in[26];
    const float* bias_jv = (const float*)d_in[27];
    const float* W_host   = (const float*)d_in[28];
    const float* b_host   = (const float*)d_in[29];
    const float* W_vm     = (const float*)d_in[30];
    const float* b_vm     = (const float*)d_in[31];
    const float* W_job    = (const float*)d_in[32];
    const float* b_job    = (const float*)d_in[33];
    const float* W_switch = (const float*)d_in[34];
    const float* b_switch = (const float*)d_in[35];

    const int NH  = in_sizes[0] / 64;
    const int NV  = in_sizes[1] / 64;
    const int NJ  = in_sizes[2] / 64;
    const int NSW = in_sizes[3] / 64;
    const int EHS = in_sizes[4];
    const int EVH = in_sizes[6];
    const int EJV = in_sizes[8];
    const int Etot = EHS + EVH + EJV;

    float* out = (float*)d_out;
    float* s_host = out;
    float* s_vm = out + NH;
    float* s_job = out + NH + NV;
    float* s_sw = out + NH + NV + NJ;
    float* a_hs = out + NH + NV + NJ + NSW;
    float* a_vh = a_hs + (size_t)EHS * 4;
    float* a_jv = a_vh + (size_t)EVH * 4;

    const int pb1 = ((NSW + 255) / 256) * 256;
    const int pb2 = pb1 + ((NH + 255) / 256) * 256;
    const int ptot = pb2 + ((NV + 255) / 256) * 256;

    // -------- ws layout (~137 MB total) --------
    float* ws = (float*)d_ws;
    int2* nxt_all = (int2*)ws;                              // Etot int2
    int* head_all = (int*)(nxt_all + Etot);                 // ptot
    float* dn_all = (float*)(head_all + ptot);              // ptot*4
    __half* Wt    = (__half*)(dn_all + (size_t)ptot * 4);   // 6*8192 fp16
    __half* mats  = Wt + 6 * 8192;
    __half* xl_hs = mats;                                   // NH*128
    __half* xr_hs = xl_hs + (size_t)NH * 128;               // NSW*128
    __half* xl_vh = xr_hs + (size_t)NSW * 128;              // NV*128
    __half* xr_vh = xl_vh + (size_t)NV * 128;               // NH*128
    __half* xl_jv = xr_vh + (size_t)NH * 128;               // NJ*128
    __half* xr_jv = xl_jv + (size_t)NJ * 128;               // NV*128

    // L0: head = -1 + Wt conversion + job scores (constant)
    {
        WSrc w;
        w.W[0] = Wl_hs; w.W[1] = Wr_hs; w.W[2] = Wl_vh;
        w.W[3] = Wr_vh; w.W[4] = Wl_jv; w.W[5] = Wr_jv;
        int tot = ptot + 6 * 8192 + NJ;
        init_wt_kernel<<<(tot + 255) / 256, 256, 0, stream>>>(
            head_all, ptot, w, Wt, b_job, s_job, NJ);
    }

    // L1: link (standalone, isolated counters)
    link_kernel<<<768, 256, 0, stream>>>(
        e_hs_dst, e_hs_src, e_vh_dst, e_vh_src, e_jv_dst, e_jv_src,
        head_all, nxt_all, EHS, EVH, EJV, pb1, pb2);

    // L2: pure persistent GEMM (isolated counters)
    {
        GemmJobs j;
        const float* Xs[6] = {x_host, x_switch, x_vm, x_host, x_job, x_vm};
        const float* bs[6] = {bl_hs, br_hs, bl_vh, br_vh, bl_jv, br_jv};
        __half* Ys[6] = {xl_hs, xr_hs, xl_vh, xr_vh, xl_jv, xr_jv};
        int Ms[6] = {NH, NSW, NV, NH, NJ, NV};
        int nbk[6]; long long total_nb = 0;
        for (int k = 0; k < 6; k++) { nbk[k] = (Ms[k] + 63) / 64; total_nb += nbk[k]; }
        const int GBTOT = 2048;     // all blocks are GEMM workers now
        int pb = 0;
        for (int k = 0; k < 6; k++) {
            j.X[k] = Xs[k]; j.b[k] = bs[k]; j.Y[k] = Ys[k]; j.M[k] = Ms[k];
            j.pbase[k] = pb;
            int gb = (int)(((long long)GBTOT * nbk[k]) / total_nb);
            if (gb < 1) gb = 1;
            pb += gb;
        }
        j.pbase[6] = pb;
        gemm_kernel<<<pb, 256, 0, stream>>>(j, Wt);
    }

    // L3: merged agg (3 relations, 32 dst per block)
    {
        AggJobs aj;
        aj.r[0] = {xl_hs, xr_hs, att_hs, head_all + 0, nxt_all + 0,
                   a_hs, dn_all + 0,
                   bias_hs, W_switch, b_switch, s_sw, NSW};
        aj.r[1] = {xl_vh, xr_vh, att_vh, head_all + pb1, nxt_all + EHS,
                   a_vh, dn_all + (size_t)pb1 * 4,
                   bias_vh, W_host, b_host, s_host, NH};
        aj.r[2] = {xl_jv, xr_jv, att_jv, head_all + pb2, nxt_all + (EHS + EVH),
                   a_jv, dn_all + (size_t)pb2 * 4,
                   bias_jv, W_vm, b_vm, s_vm, NV};
        aj.base[0] = 0;
        aj.base[1] = (NSW + 31) / 32;
        aj.base[2] = aj.base[1] + (NH + 31) / 32;
        aj.base[3] = aj.base[2] + (NV + 31) / 32;
        agg3_kernel<<<aj.base[3], 256, 0, stream>>>(aj);
    }

    // L4: alpha (all relations)
    {
        int ab = (Etot * 4 + 255) / 256;
        alpha_kernel<<<ab, 256, 0, stream>>>(
            a_hs, e_hs_dst, e_vh_dst, e_jv_dst, dn_all,
            EHS, EVH, EJV, pb1, pb2);
    }
}

// Round 9
// 366.703 us; speedup vs baseline: 1.3356x; 1.1086x over previous
//
#include <hip/hip_runtime.h>
#include <hip/hip_fp16.h>

// ---------------------------------------------------------------------------
// HeteroIncidentGATv2: 3 bipartite GATv2 relations (H=4, C=32, HC=128)
//   hs: host->switch (200K), vh: vm->host (400K), jv: job->vm (800K)
//
// R21 changes vs R20 (406.5us; split REGRESSED +39us vs merged -> link+GEMM
// overlap constructively; revert to merged R15 structure):
//   - mega re-merged exactly as R15 (best measured, 367.5us) EXCEPT the 384
//     link blocks now JOIN the GEMM at HALF WEIGHT after linking: tiles are
//     partitioned over 1856 virtual slots = 1664 full (GEMM-only blocks) +
//     192 half (pairs of link blocks split one slot's tile walk by parity).
//     Static assignment -> no R19-style ticket starvation; link blocks'
//     GEMM share (~42us) + link (~20us) ~ balances GEMM-only share (~85us).
//   - agg3 / alpha / init unchanged from R20 (= R15 structure).
// ---------------------------------------------------------------------------

#define SLOPE_ATT 0.2f
#define SLOPE_OUT 0.01f

typedef _Float16 half8_t __attribute__((ext_vector_type(8)));
typedef _Float16 v2h_t __attribute__((ext_vector_type(2)));
typedef float float4_t __attribute__((ext_vector_type(4)));

__device__ __forceinline__ float dot8(half8_t a, half8_t b, float acc) {
    v2h_t a0 = __builtin_shufflevector(a, a, 0, 1);
    v2h_t a1 = __builtin_shufflevector(a, a, 2, 3);
    v2h_t a2 = __builtin_shufflevector(a, a, 4, 5);
    v2h_t a3 = __builtin_shufflevector(a, a, 6, 7);
    v2h_t b0 = __builtin_shufflevector(b, b, 0, 1);
    v2h_t b1 = __builtin_shufflevector(b, b, 2, 3);
    v2h_t b2 = __builtin_shufflevector(b, b, 4, 5);
    v2h_t b3 = __builtin_shufflevector(b, b, 6, 7);
    acc = __builtin_amdgcn_fdot2(a0, b0, acc, false);
    acc = __builtin_amdgcn_fdot2(a1, b1, acc, false);
    acc = __builtin_amdgcn_fdot2(a2, b2, acc, false);
    acc = __builtin_amdgcn_fdot2(a3, b3, acc, false);
    return acc;
}

// ---------------------------------------------------------------------------
// L0: head = -1 + Wt fp16 transpose + job scores (= sigmoid(b_job), const).
// ---------------------------------------------------------------------------
struct WSrc { const float* W[6]; };

__global__ __launch_bounds__(256) void init_wt_kernel(
    int* __restrict__ head, int ptot, WSrc wsrc, __half* __restrict__ Wt,
    const float* __restrict__ bjob, float* __restrict__ sjob, int NJ) {
    int i = blockIdx.x * 256 + threadIdx.x;
    if (i < ptot) {
        head[i] = -1;
    } else {
        int r = i - ptot;
        if (r < 6 * 8192) {
            int j = r >> 13;           // which W
            int rr = r & 8191;         // n*64 + k
            int n = rr >> 6, k = rr & 63;
            Wt[r] = (__half)wsrc.W[j][k * 128 + n];
        } else {
            int q = r - 6 * 8192;
            if (q < NJ) sjob[q] = 1.f / (1.f + __expf(-bjob[0]));
        }
    }
}

// ---------------------------------------------------------------------------
// Linked-list build: old = atomicExch(&head[slot], le); nxt[ge] = {old, src}
// ---------------------------------------------------------------------------
__device__ __forceinline__ void link_work(
    int linkId, int linkBlocks,
    const int* __restrict__ d0, const int* __restrict__ s0,
    const int* __restrict__ d1, const int* __restrict__ s1,
    const int* __restrict__ d2, const int* __restrict__ s2,
    int* __restrict__ head, int2* __restrict__ nxt,
    int E0, int E1, int E2, int pb1, int pb2) {
    int i = linkId * 256 + threadIdx.x;
    int Etot = E0 + E1 + E2;
    int stride = linkBlocks * 256;
    for (; i < Etot; i += stride) {
        int le, slot; const int* sp;
        if (i < E0)           { le = i;           slot = d0[le];       sp = s0; }
        else if (i < E0 + E1) { le = i - E0;      slot = pb1 + d1[le]; sp = s1; }
        else                  { le = i - E0 - E1; slot = pb2 + d2[le]; sp = s2; }
        int old = atomicExch(&head[slot], le);
        nxt[i] = make_int2(old, sp[le]);
    }
}

// ---------------------------------------------------------------------------
// Mega: link3 (first LB blocks) + persistent GEMM over weighted slots.
// Slots: blocks >= LB own slot (b-LB), walk tiles {p, p+gb, ...}.
//        blocks <  LB pair up on slot NS1+(b>>1), walking alternate tiles
//        {p+(b&1)*gb, step 2*gb} AFTER doing link work (half weight).
// Frag layouts (gfx950 16x16x32): A[m=lane&15][k=quad*8+j],
// B[n=lane&15][k=quad*8+j], C/D col=lane&15, row=quad*4+reg.
// W frags + bias loop-invariant registers; X prefetched 1 tile ahead.
// No barrier: sY[wv] slice is wave-private, DS pipe is in-order per wave.
// ---------------------------------------------------------------------------
struct GemmJobs {
    const float* X[6]; const float* b[6]; __half* Y[6];
    int M[6]; int pbase[7];     // slot partition (over NS1 + LB/2 slots)
};

__global__ __launch_bounds__(256) void mega_gemm_link_kernel(
    GemmJobs j, const __half* __restrict__ Wt, int LB, int NS1,
    const int* __restrict__ d0, const int* __restrict__ s0,
    const int* __restrict__ d1, const int* __restrict__ s1,
    const int* __restrict__ d2, const int* __restrict__ s2,
    int* __restrict__ head, int2* __restrict__ nxt,
    int E0, int E1, int E2, int pb1, int pb2) {
    __shared__ __half sY[4][16][136];
    int b = blockIdx.x;
    int slot, par;
    if (b < LB) {
        link_work(b, LB, d0, s0, d1, s1, d2, s2, head, nxt, E0, E1, E2, pb1, pb2);
        slot = NS1 + (b >> 1);
        par = (b & 1) + 1;          // par>0 marks half-weight: start p+(par-1)*gb, step 2*gb
    } else {
        slot = b - LB;
        par = 0;
    }

    int k = 0;
    while (slot >= j.pbase[k + 1]) k++;
    const int p = slot - j.pbase[k];
    const int gb = j.pbase[k + 1] - j.pbase[k];
    const int M = j.M[k];
    const int nb = (M + 63) >> 6;
    const int start = par ? p + (par - 1) * gb : p;
    const int step = par ? gb * 2 : gb;
    if (start >= nb) return;
    const float* __restrict__ X = j.X[k];
    __half* __restrict__ Y = j.Y[k];
    const float* __restrict__ bb_ = j.b[k];
    const __half* __restrict__ W = Wt + (size_t)k * 8192;

    const int lane = threadIdx.x & 63;
    const int wv = threadIdx.x >> 6;
    const int mr = lane & 15;
    const int quad = lane >> 4;

    // loop-invariant: all 16 W fragments + 8 bias values live in registers
    half8_t wb0[8], wb1[8];
    float bv[8];
#pragma unroll
    for (int t = 0; t < 8; t++) {
        const __half* wp = W + ((size_t)(t * 16 + mr)) * 64 + quad * 8;
        wb0[t] = *(const half8_t*)wp;
        wb1[t] = *(const half8_t*)(wp + 32);
        bv[t] = bb_[t * 16 + mr];
    }

    // prefetch first X tile
    float4 xc0 = {}, xc1 = {}, xc2 = {}, xc3 = {};
    {
        int gr = start * 64 + wv * 16 + mr;
        if (gr < M) {
            const float4* xp = (const float4*)(X + (size_t)gr * 64 + quad * 8);
            xc0 = xp[0]; xc1 = xp[1];
            const float4* xq = (const float4*)(X + (size_t)gr * 64 + 32 + quad * 8);
            xc2 = xq[0]; xc3 = xq[1];
        }
    }

    for (int t = start; t < nb; t += step) {
        // issue next tile's X loads first (in flight across this iteration)
        int tn = t + step;
        float4 xn0 = {}, xn1 = {}, xn2 = {}, xn3 = {};
        if (tn < nb) {
            int gr = tn * 64 + wv * 16 + mr;
            if (gr < M) {
                const float4* xp = (const float4*)(X + (size_t)gr * 64 + quad * 8);
                xn0 = xp[0]; xn1 = xp[1];
                const float4* xq = (const float4*)(X + (size_t)gr * 64 + 32 + quad * 8);
                xn2 = xq[0]; xn3 = xq[1];
            }
        }

        half8_t a0, a1;
        a0[0] = (_Float16)xc0.x; a0[1] = (_Float16)xc0.y;
        a0[2] = (_Float16)xc0.z; a0[3] = (_Float16)xc0.w;
        a0[4] = (_Float16)xc1.x; a0[5] = (_Float16)xc1.y;
        a0[6] = (_Float16)xc1.z; a0[7] = (_Float16)xc1.w;
        a1[0] = (_Float16)xc2.x; a1[1] = (_Float16)xc2.y;
        a1[2] = (_Float16)xc2.z; a1[3] = (_Float16)xc2.w;
        a1[4] = (_Float16)xc3.x; a1[5] = (_Float16)xc3.y;
        a1[6] = (_Float16)xc3.z; a1[7] = (_Float16)xc3.w;

        const int m0 = t * 64 + wv * 16;
#pragma unroll
        for (int tt = 0; tt < 8; tt++) {
            float4_t c = {0.f, 0.f, 0.f, 0.f};
            c = __builtin_amdgcn_mfma_f32_16x16x32_f16(a0, wb0[tt], c, 0, 0, 0);
            c = __builtin_amdgcn_mfma_f32_16x16x32_f16(a1, wb1[tt], c, 0, 0, 0);
            int ocol = tt * 16 + mr;
            int lrow = quad * 4;
#pragma unroll
            for (int r = 0; r < 4; r++)
                sY[wv][lrow + r][ocol] = (__half)(c[r] + bv[tt]);
        }

        // wave-private LDS transpose -> coalesced 16B stores (no barrier)
        const int c8 = mr * 8;
#pragma unroll
        for (int i = 0; i < 4; i++) {
            int row = i * 4 + quad;
            int gr2 = m0 + row;
            if (gr2 < M) {
                half8_t v = *(const half8_t*)&sY[wv][row][c8];
                *(half8_t*)&Y[(size_t)gr2 * 128 + c8] = v;
            }
        }

        xc0 = xn0; xc1 = xn1; xc2 = xn2; xc3 = xn3;
    }
}

// ---------------------------------------------------------------------------
// Fused GATv2 aggregate: 32 dst per 256-thread block (8 lanes/dst, 16 ch/ln).
// Per edge: in-lane fdot2 + one shfl -> head logit; w = exp(p); acc += w*x;
// ex[e] = w (unnormalized), dn[d] = ssum. Fused readout epilogue.
// ---------------------------------------------------------------------------
struct AggJob {
    const __half* xl; const __half* xr; const float* att;
    const int* head; const int2* nxt;
    float* ex; float* dn;
    const float* bias; const float* Wn; const float* bn; float* scores;
    int Nd;
};
struct AggJobs { AggJob r[3]; int base[4]; };   // base in BLOCKS (32 dst/block)

__global__ __launch_bounds__(256) void agg3_kernel(AggJobs aj) {
    int b = blockIdx.x;
    int k = 0;
    while (b >= aj.base[k + 1]) k++;
    AggJob J = aj.r[k];

    const int l = threadIdx.x & 63;
    const int wv = threadIdx.x >> 6;
    const int li = l & 7;                 // lane in group
    const int g = l >> 3;                 // group 0..7
    const int dbase = ((b - aj.base[k]) * 4 + wv) * 8;
    const int d = dbase + g;
    if (dbase >= J.Nd) return;
    const bool dok = d < J.Nd;
    const int h = li >> 1;                // my head (pair of lanes per head)

    // my 16 channels: 2 x half8
    half8_t xr0 = {}, xr1 = {};
    if (dok) {
        const half8_t* xrp = (const half8_t*)(J.xr + (size_t)d * 128) + li * 2;
        xr0 = xrp[0]; xr1 = xrp[1];
    }
    half8_t at0, at1;
    {
        const float* ap = J.att + li * 16;
#pragma unroll
        for (int i = 0; i < 8; i++) {
            at0[i] = (_Float16)ap[i];
            at1[i] = (_Float16)ap[8 + i];
        }
    }
    const half8_t sl8 = {(_Float16)SLOPE_ATT, (_Float16)SLOPE_ATT,
                         (_Float16)SLOPE_ATT, (_Float16)SLOPE_ATT,
                         (_Float16)SLOPE_ATT, (_Float16)SLOPE_ATT,
                         (_Float16)SLOPE_ATT, (_Float16)SLOPE_ATT};

    float acc[16] = {};
    float ssum = 0.f;

    int e = dok ? J.head[d] : -1;
    const bool any = (e >= 0);

    while (__any(e >= 0)) {
        bool act = (e >= 0);
        int2 ns = act ? J.nxt[e] : make_int2(-1, 0);
        half8_t x0 = {}, x1 = {};
        if (act) {
            const half8_t* xp = (const half8_t*)(J.xl + (size_t)ns.y * 128) + li * 2;
            x0 = xp[0]; x1 = xp[1];
        }
        if (act) {
            half8_t v0 = x0 + xr0;
            half8_t v1 = x1 + xr1;
            half8_t lk0 = __builtin_elementwise_max(v0, v0 * sl8);
            half8_t lk1 = __builtin_elementwise_max(v1, v1 * sl8);
            float p = dot8(lk1, at1, dot8(lk0, at0, 0.f));
            p += __shfl_xor(p, 1);            // pair shares one head
            float w = __expf(p);
            if ((li & 1) == 0) J.ex[(size_t)e * 4 + h] = w;
            ssum += w;
#pragma unroll
            for (int i = 0; i < 8; i++) {
                acc[i]     += w * (float)x0[i];
                acc[8 + i] += w * (float)x1[i];
            }
        }
        e = act ? ns.x : -1;
    }

    if (dok && (li & 1) == 0) J.dn[(size_t)d * 4 + h] = ssum;

    // readout: sigmoid(lrelu(acc/ssum + bias, .01) . Wn + bn)
    float rr = any ? 1.f / ssum : 0.f;
    float pr = 0.f;
    if (dok) {
        const float* bp = J.bias + li * 16;
        const float* wp = J.Wn + li * 16;
#pragma unroll
        for (int i = 0; i < 16; i++) {
            float o = acc[i] * rr + bp[i];
            o = o > 0.f ? o : SLOPE_OUT * o;
            pr += o * wp[i];
        }
    }
    pr += __shfl_xor(pr, 1);
    pr += __shfl_xor(pr, 2);
    pr += __shfl_xor(pr, 4);
    if (dok && li == 0)
        J.scores[d] = 1.f / (1.f + __expf(-(pr + J.bn[0])));
}

// ---------------------------------------------------------------------------
// alpha = ex/dn for all relations (job scores handled in init).
// ---------------------------------------------------------------------------
__global__ __launch_bounds__(256) void alpha_kernel(
    float* __restrict__ ex,
    const int* __restrict__ d0, const int* __restrict__ d1,
    const int* __restrict__ d2,
    const float* __restrict__ dn,
    int E0, int E1, int E2, int pb1, int pb2) {
    int i = blockIdx.x * 256 + threadIdx.x;
    int tot = (E0 + E1 + E2) * 4;
    if (i >= tot) return;
    int e = i >> 2, h = i & 3;
    int d;
    if (e < E0)           d = d0[e];
    else if (e < E0 + E1) d = pb1 + d1[e - E0];
    else                  d = pb2 + d2[e - E0 - E1];
    ex[i] = ex[i] / dn[(size_t)d * 4 + h];
}

// ---------------------------------------------------------------------------

extern "C" void kernel_launch(void* const* d_in, const int* in_sizes, int n_in,
                              void* d_out, int out_size, void* d_ws, size_t ws_size,
                              hipStream_t stream) {
    const float* x_host   = (const float*)d_in[0];
    const float* x_vm     = (const float*)d_in[1];
    const float* x_job    = (const float*)d_in[2];
    const float* x_switch = (const float*)d_in[3];
    const int* e_hs_src = (const int*)d_in[4];
    const int* e_hs_dst = (const int*)d_in[5];
    const int* e_vh_src = (const int*)d_in[6];
    const int* e_vh_dst = (const int*)d_in[7];
    const int* e_jv_src = (const int*)d_in[8];
    const int* e_jv_dst = (const int*)d_in[9];
    const float* Wl_hs = (const float*)d_in[10];
    const float* bl_hs = (const float*)d_in[11];
    const float* Wr_hs = (const float*)d_in[12];
    const float* br_hs = (const float*)d_in[13];
    const float* att_hs = (const float*)d_in[14];
    const float* bias_hs = (const float*)d_in[15];
    const float* Wl_vh = (const float*)d_in[16];
    const float* bl_vh = (const float*)d_in[17];
    const float* Wr_vh = (const float*)d_in[18];
    const float* br_vh = (const float*)d_in[19];
    const float* att_vh = (const float*)d_in[20];
    const float* bias_vh = (const float*)d_in[21];
    const float* Wl_jv = (const float*)d_in[22];
    const float* bl_jv = (const float*)d_in[23];
    const float* Wr_jv = (const float*)d_in[24];
    const float* br_jv = (const float*)d_in[25];
    const float* att_jv = (const float*)d_in[26];
    const float* bias_jv = (const float*)d_in[27];
    const float* W_host   = (const float*)d_in[28];
    const float* b_host   = (const float*)d_in[29];
    const float* W_vm     = (const float*)d_in[30];
    const float* b_vm     = (const float*)d_in[31];
    const float* W_job    = (const float*)d_in[32];
    const float* b_job    = (const float*)d_in[33];
    const float* W_switch = (const float*)d_in[34];
    const float* b_switch = (const float*)d_in[35];

    const int NH  = in_sizes[0] / 64;
    const int NV  = in_sizes[1] / 64;
    const int NJ  = in_sizes[2] / 64;
    const int NSW = in_sizes[3] / 64;
    const int EHS = in_sizes[4];
    const int EVH = in_sizes[6];
    const int EJV = in_sizes[8];
    const int Etot = EHS + EVH + EJV;

    float* out = (float*)d_out;
    float* s_host = out;
    float* s_vm = out + NH;
    float* s_job = out + NH + NV;
    float* s_sw = out + NH + NV + NJ;
    float* a_hs = out + NH + NV + NJ + NSW;
    float* a_vh = a_hs + (size_t)EHS * 4;
    float* a_jv = a_vh + (size_t)EVH * 4;

    const int pb1 = ((NSW + 255) / 256) * 256;
    const int pb2 = pb1 + ((NH + 255) / 256) * 256;
    const int ptot = pb2 + ((NV + 255) / 256) * 256;

    // -------- ws layout (~137 MB total) --------
    float* ws = (float*)d_ws;
    int2* nxt_all = (int2*)ws;                              // Etot int2
    int* head_all = (int*)(nxt_all + Etot);                 // ptot
    float* dn_all = (float*)(head_all + ptot);              // ptot*4
    __half* Wt    = (__half*)(dn_all + (size_t)ptot * 4);   // 6*8192 fp16
    __half* mats  = Wt + 6 * 8192;
    __half* xl_hs = mats;                                   // NH*128
    __half* xr_hs = xl_hs + (size_t)NH * 128;               // NSW*128
    __half* xl_vh = xr_hs + (size_t)NSW * 128;              // NV*128
    __half* xr_vh = xl_vh + (size_t)NV * 128;               // NH*128
    __half* xl_jv = xr_vh + (size_t)NH * 128;               // NJ*128
    __half* xr_jv = xl_jv + (size_t)NJ * 128;               // NV*128

    // L0: head = -1 + Wt conversion + job scores (constant)
    {
        WSrc w;
        w.W[0] = Wl_hs; w.W[1] = Wr_hs; w.W[2] = Wl_vh;
        w.W[3] = Wr_vh; w.W[4] = Wl_jv; w.W[5] = Wr_jv;
        int tot = ptot + 6 * 8192 + NJ;
        init_wt_kernel<<<(tot + 255) / 256, 256, 0, stream>>>(
            head_all, ptot, w, Wt, b_job, s_job, NJ);
    }

    // L1: mega = link3 + persistent GEMM over weighted slots
    {
        GemmJobs j;
        const float* Xs[6] = {x_host, x_switch, x_vm, x_host, x_job, x_vm};
        const float* bs[6] = {bl_hs, br_hs, bl_vh, br_vh, bl_jv, br_jv};
        __half* Ys[6] = {xl_hs, xr_hs, xl_vh, xr_vh, xl_jv, xr_jv};
        int Ms[6] = {NH, NSW, NV, NH, NJ, NV};
        int nbk[6]; long long total_nb = 0;
        for (int k = 0; k < 6; k++) { nbk[k] = (Ms[k] + 63) / 64; total_nb += nbk[k]; }
        const int LB = 384;         // link blocks (half-weight GEMM joiners)
        const int NS1 = 1664;       // full-weight slots
        const int NSLOTS = NS1 + LB / 2;   // 1856 virtual slots
        int pb = 0;
        for (int k = 0; k < 6; k++) {
            j.X[k] = Xs[k]; j.b[k] = bs[k]; j.Y[k] = Ys[k]; j.M[k] = Ms[k];
            j.pbase[k] = pb;
            int gb = (int)(((long long)NSLOTS * nbk[k]) / total_nb);
            if (gb < 1) gb = 1;
            pb += gb;
        }
        j.pbase[6] = pb;            // pb <= NSLOTS; trailing slots idle-safe
        mega_gemm_link_kernel<<<NS1 + LB, 256, 0, stream>>>(
            j, Wt, LB, pb > NS1 ? NS1 : NS1, e_hs_dst, e_hs_src,
            e_vh_dst, e_vh_src, e_jv_dst, e_jv_src,
            head_all, nxt_all, EHS, EVH, EJV, pb1, pb2);
    }

    // L2: merged agg (3 relations, 32 dst per block)
    {
        AggJobs aj;
        aj.r[0] = {xl_hs, xr_hs, att_hs, head_all + 0, nxt_all + 0,
                   a_hs, dn_all + 0,
                   bias_hs, W_switch, b_switch, s_sw, NSW};
        aj.r[1] = {xl_vh, xr_vh, att_vh, head_all + pb1, nxt_all + EHS,
                   a_vh, dn_all + (size_t)pb1 * 4,
                   bias_vh, W_host, b_host, s_host, NH};
        aj.r[2] = {xl_jv, xr_jv, att_jv, head_all + pb2, nxt_all + (EHS + EVH),
                   a_jv, dn_all + (size_t)pb2 * 4,
                   bias_jv, W_vm, b_vm, s_vm, NV};
        aj.base[0] = 0;
        aj.base[1] = (NSW + 31) / 32;
        aj.base[2] = aj.base[1] + (NH + 31) / 32;
        aj.base[3] = aj.base[2] + (NV + 31) / 32;
        agg3_kernel<<<aj.base[3], 256, 0, stream>>>(aj);
    }

    // L3: alpha (all relations)
    {
        int ab = (Etot * 4 + 255) / 256;
        alpha_kernel<<<ab, 256, 0, stream>>>(
            a_hs, e_hs_dst, e_vh_dst, e_jv_dst, dn_all,
            EHS, EVH, EJV, pb1, pb2);
    }
}